// Round 7
// baseline (497.482 us; speedup 1.0000x reference)
//
#include <hip/hip_runtime.h>
#include <hip/hip_bf16.h>

#define BB 32
#define TT 1600
#define EE 1024
#define AA 512
#define CC 10
#define KW 201

typedef __attribute__((ext_vector_type(8))) short short8;
typedef __attribute__((ext_vector_type(4))) float f32x4;

__device__ __forceinline__ float sigm(float x) { return 1.f / (1.f + expf(-x)); }

// pack 2 floats -> 2 bf16 (RNE): v_cvt_pk_bf16_f32
__device__ __forceinline__ unsigned int cvt2(float a, float b) {
    float2 f2; f2.x = a; f2.y = b;
    __hip_bfloat162 h = __float22bfloat162_rn(f2);
    unsigned int r;
    __builtin_memcpy(&r, &h, 4);
    return r;
}

// async global->LDS 16 B/lane (global_load_lds_dwordx4); dest must be lane-linear
__device__ __forceinline__ void gl_lds16(const void* g, void* l) {
    __builtin_amdgcn_global_load_lds(
        (const __attribute__((address_space(1))) unsigned int*)g,
        (__attribute__((address_space(3))) unsigned int*)l, 16, 0, 0);
}

// ---------------- ws layout (float units) ----------------
#define AF_OFF   0        // att_feat 32*10 = 320
#define R_OFF    320      // r = h_new + dec_proj: 16384
#define E_OFF    16704    // e partial scores: 2 x 51200 (col-half partials)
#define WBF_OFF  119104   // W_enc bf16: 524288 shorts = 262144 floats
// total ~381K floats = 1.49 MB

// ---------------- out layout (float units) ----------------
#define CTX_OFF 0
#define W_OFF   32768
#define H_OFF   83968
#define C_OFF   100352

// K1: blocks 0..319 = location conv (one block per (b,c), full T, no atomics);
//     blocks 320..831 = W_enc f32->bf16 conversion
__global__ void prep_kernel(const float* __restrict__ att_prev,
                            const float* __restrict__ conv_w,
                            const float* __restrict__ W_enc,
                            float* __restrict__ af,
                            unsigned short* __restrict__ Wbf) {
    int bx = blockIdx.x, tid = threadIdx.x;
    if (bx >= 320) {
        int i = (bx - 320) * 256 + tid;   // float4 unit, 131072 total
        float4 v = reinterpret_cast<const float4*>(W_enc)[i];
        uint2 p;
        p.x = cvt2(v.x, v.y);
        p.y = cvt2(v.z, v.w);
        reinterpret_cast<uint2*>(Wbf)[i] = p;
        return;
    }
    int b = bx / 10, c = bx % 10;
    __shared__ float xs[1808];     // t in [-100, 1707], padded
    __shared__ float wsm[KW];
    __shared__ float red[256];
    const float* xp = att_prev + b * TT;
    for (int i = tid; i < 1808; i += 256) {
        int g = i - 100;
        xs[i] = (g >= 0 && g < TT) ? xp[g] : 0.f;
    }
    if (tid < KW) wsm[tid] = conv_w[c * KW + tid];
    __syncthreads();
    float mx = 0.f;   // relu >= 0 so 0 is a valid identity
    #pragma unroll 1
    for (int sweep = 0; sweep < 2; ++sweep) {
        int t0 = sweep * 1024 + tid * 4;
        if (t0 >= TT) break;
        // rolling window: s_j = sum_k w[k]*xs[t0+j+k]
        float a0 = xs[t0], a1 = xs[t0 + 1], a2 = xs[t0 + 2], a3 = xs[t0 + 3];
        float s0 = 0.f, s1 = 0.f, s2 = 0.f, s3 = 0.f;
        #pragma unroll 4
        for (int k = 0; k < KW; ++k) {
            float w = wsm[k];
            s0 += w * a0; s1 += w * a1; s2 += w * a2; s3 += w * a3;
            a0 = a1; a1 = a2; a2 = a3;
            a3 = xs[t0 + k + 4];
        }
        mx = fmaxf(mx, fmaxf(fmaxf(s0, s1), fmaxf(s2, s3)));
    }
    red[tid] = mx; __syncthreads();
    for (int s = 128; s > 0; s >>= 1) {
        if (tid < s) red[tid] = fmaxf(red[tid], red[tid + s]);
        __syncthreads();
    }
    if (tid == 0) af[b * CC + c] = red[0];
}

// K2: gates + dec_proj + LSTM + r, one block per 2 a-values (grid 256, 512 thr).
__global__ void gates_lstm_kernel(const float* __restrict__ af,
                                  const float* __restrict__ att_h,
                                  const float* __restrict__ dec_z,
                                  const float* __restrict__ att_c,
                                  const float* __restrict__ W_ih,
                                  const float* __restrict__ W_hh,
                                  const float* __restrict__ W_dec,
                                  float* __restrict__ out,
                                  float* __restrict__ r_ws) {
    __shared__ float gsm[8][32];
    __shared__ float dsm[8][32];
    int tid = threadIdx.x;
    int a0 = blockIdx.x * 2;
    int b = tid & 31;
    if (tid < 256) {
        int u = tid >> 5;                 // 0..7 = gate*2 + ai
        int gate = u >> 1, ai = u & 1;
        int j = gate * 512 + a0 + ai;
        float s = 0.f;
        #pragma unroll
        for (int k = 0; k < 10; ++k) s += af[b * 10 + k] * W_ih[j * 10 + k];
        const float4* wr = reinterpret_cast<const float4*>(W_hh + (size_t)j * 512);
        const float4* hr = reinterpret_cast<const float4*>(att_h + b * 512);
        #pragma unroll 4
        for (int k = 0; k < 128; ++k) {
            float4 w = wr[k], h = hr[k];
            s += w.x * h.x + w.y * h.y + w.z * h.z + w.w * h.w;
        }
        gsm[u][b] = s;
    } else {
        int v = (tid - 256) >> 5;         // 0..7 = q*2 + ai
        int ai = v & 1, q = v >> 1;
        int a = a0 + ai;
        const float4* wr = reinterpret_cast<const float4*>(W_dec + (size_t)a * 1024) + q * 64;
        const float4* zr = reinterpret_cast<const float4*>(dec_z + (size_t)b * 1024) + q * 64;
        float s = 0.f;
        #pragma unroll 4
        for (int k = 0; k < 64; ++k) {
            float4 w = wr[k], z = zr[k];
            s += w.x * z.x + w.y * z.y + w.z * z.z + w.w * z.w;
        }
        dsm[v][b] = s;
    }
    __syncthreads();
    if (tid < 64) {
        int ai = tid >> 5;
        int a = a0 + ai;
        float ig = gsm[ai][b], fg = gsm[2 + ai][b], gg = gsm[4 + ai][b], og = gsm[6 + ai][b];
        float cn = sigm(fg) * att_c[b * 512 + a] + sigm(ig) * tanhf(gg);
        float hn = sigm(og) * tanhf(cn);
        out[H_OFF + b * 512 + a] = hn;
        out[C_OFF + b * 512 + a] = cn;
        float dec = dsm[ai][b] + dsm[2 + ai][b] + dsm[4 + ai][b] + dsm[6 + ai][b];
        r_ws[b * 512 + a] = hn + dec;
    }
}

// K3: fused score GEMM, restructured for 2 blocks/CU (the R0-R6 invariant was
// 1 block/CU: every barrier drained the whole CU with no sibling block to fill
// the stall — m97's 874 TF comes from 3 blocks/CU with a simple schedule).
// Block = 512 thr (8 waves, 2m x 4n, wave 64x64), tile 128M x 256N, BK=32.
// __launch_bounds__(512,4) -> 2 blocks/CU; LDS 64 KB/block (Af dbuf 32K + Bs
// dbuf 32K). N is split in two col-halves: each block emits a PARTIAL e over its
// 256 n's (tanh is elementwise, the n-sum separable); ctx adds the two partials.
// A re-read x2 is L3-absorbed (enc 205 MB < 256 MB L3; col-pair blocks adjacent).
// ALL staging via global_load_lds (A as f32, cvt-on-read; ZERO staging registers
// -> no spill by construction). Simple proven m97 schedule: stage(c+1) -> frags
// + MFMA -> one __syncthreads() per chunk; cross-block overlap hides the drain.
__global__ void __launch_bounds__(512, 4)
score_gemm_kernel(const float* __restrict__ enc,
                  const unsigned short* __restrict__ Wbf,
                  const float* __restrict__ b_enc,
                  const float* __restrict__ r_ws,
                  const float* __restrict__ W_g,
                  float* __restrict__ e_ws) {
    __shared__ __align__(16) short Bs[2][8192];   // 2 x (256n x 32k) bf16, 32 KB
    __shared__ __align__(16) float Af[2][4096];   // 2 x (128m x 32k) f32, 32 KB

    int tid = threadIdx.x;
    int lane = tid & 63, wv = tid >> 6;
    int wm = wv >> 2, wn = wv & 3;
    int col = lane & 15, quad = lane >> 4;
    int mblk = blockIdx.x >> 1, cb = blockIdx.x & 1;
    int m0 = mblk * 128;

    // A staging (f32, 16 KB/tile, 2 issues x 8 KB): issue j, thread t covers
    // mgrp = j*4 + (t>>7), slot = t&127 (kq=slot>>4, row=slot&15) -> 16 B.
    const float* asrc0 = enc + (size_t)(m0 + (tid >> 7) * 16 + (tid & 15)) * EE
                             + ((tid & 127) >> 4) * 4;
    const float* asrc1 = asrc0 + (size_t)64 * EE;
    // B staging (bf16, 16 KB/tile, 2 issues x 8 KB): issue j, thread t covers
    // ngrp = j*8 + (t>>6), slot = t&63 (koct=slot>>4, row=slot&15) -> 16 B.
    const unsigned short* bsrc0 = Wbf + (size_t)(cb * 256 + (tid >> 6) * 16 + (tid & 15)) * EE
                                      + ((tid & 63) >> 4) * 8;
    const unsigned short* bsrc1 = bsrc0 + (size_t)128 * EE;

    f32x4 acc[4][4];   // [mt][nt]
    #pragma unroll
    for (int mt = 0; mt < 4; ++mt)
        #pragma unroll
        for (int nt = 0; nt < 4; ++nt)
            acc[mt][nt] = (f32x4){0.f, 0.f, 0.f, 0.f};

#define STAGE(KC, BUF)                                                          \
    {                                                                           \
        gl_lds16(asrc0 + (KC) * 32, (char*)Af[BUF] + tid * 16);                 \
        gl_lds16(asrc1 + (KC) * 32, (char*)Af[BUF] + 8192 + tid * 16);          \
        gl_lds16(bsrc0 + (KC) * 32, (char*)Bs[BUF] + tid * 16);                 \
        gl_lds16(bsrc1 + (KC) * 32, (char*)Bs[BUF] + 8192 + tid * 16);          \
    }

    STAGE(0, 0)
    __syncthreads();

    #pragma unroll 2
    for (int c = 0; c < 32; ++c) {
        int buf = c & 1;
        if (c < 31) STAGE(c + 1, buf ^ 1)
        // A fragments: f32 -> bf16 on read (lane reads 2 float4 = k quad*8..+8)
        short8 afr[4];
        #pragma unroll
        for (int mt = 0; mt < 4; ++mt) {
            const float* ap = Af[buf] + (wm * 4 + mt) * 512;
            float4 x = *reinterpret_cast<const float4*>(ap + quad * 128 + col * 4);
            float4 y = *reinterpret_cast<const float4*>(ap + quad * 128 + col * 4 + 64);
            union { short8 s; unsigned int u[4]; } cv;
            cv.u[0] = cvt2(x.x, x.y); cv.u[1] = cvt2(x.z, x.w);
            cv.u[2] = cvt2(y.x, y.y); cv.u[3] = cvt2(y.z, y.w);
            afr[mt] = cv.s;
        }
        short8 bfr[4];
        #pragma unroll
        for (int nt = 0; nt < 4; ++nt)
            bfr[nt] = *reinterpret_cast<const short8*>(
                &Bs[buf][(wn * 4 + nt) * 512 + (quad * 16 + col) * 8]);
        __builtin_amdgcn_s_setprio(1);
        #pragma unroll
        for (int mt = 0; mt < 4; ++mt)
            #pragma unroll
            for (int nt = 0; nt < 4; ++nt)
                acc[mt][nt] = __builtin_amdgcn_mfma_f32_16x16x32_bf16(
                    afr[mt], bfr[nt], acc[mt][nt], 0, 0, 0);
        __builtin_amdgcn_s_setprio(0);
        __syncthreads();
    }
#undef STAGE

    // epilogue: partial e over this block's 256 n's.
    // e_part aliases Af[0] (all Af reads are behind the final barrier).
    float (*e_part)[128] = reinterpret_cast<float (*)[128]>(&Af[0][0]);
    float wg[4], bn_[4];
    #pragma unroll
    for (int nt = 0; nt < 4; ++nt) {
        int n = cb * 256 + wn * 64 + nt * 16 + col;
        wg[nt] = W_g[n];
        bn_[nt] = b_enc[n];
    }
    #pragma unroll
    for (int mt = 0; mt < 4; ++mt) {
        int mg = m0 + wm * 64 + mt * 16;   // 16-row groups never straddle batch rows
        int bb = mg / TT;
        float rr[4];
        #pragma unroll
        for (int nt = 0; nt < 4; ++nt)
            rr[nt] = r_ws[bb * AA + cb * 256 + wn * 64 + nt * 16 + col];
        #pragma unroll
        for (int reg = 0; reg < 4; ++reg) {
            float p = 0.f;
            #pragma unroll
            for (int nt = 0; nt < 4; ++nt)
                p += wg[nt] * tanhf(acc[mt][nt][reg] + bn_[nt] + rr[nt]);
            p += __shfl_xor(p, 1);
            p += __shfl_xor(p, 2);
            p += __shfl_xor(p, 4);
            p += __shfl_xor(p, 8);
            if (col == 0) e_part[wn][wm * 64 + mt * 16 + quad * 4 + reg] = p;
        }
    }
    __syncthreads();
    if (tid < 128) {
        float s = e_part[0][tid] + e_part[1][tid] + e_part[2][tid] + e_part[3][tid];
        e_ws[cb * 51200 + m0 + tid] = s;
    }
}

// K4: softmax (recomputed per block, shift-invariant so b_g dropped) + ctx chunk.
// e is now the SUM of the two col-half partials.
__global__ void ctx_softmax_kernel(const float* __restrict__ enc,
                                   const float* __restrict__ e_ws,
                                   const int* __restrict__ lens,
                                   float* __restrict__ w_out,
                                   float* __restrict__ ctx) {
    int b = blockIdx.x, ch = blockIdx.y;
    int tid = threadIdx.x;
    __shared__ float w_sm[1600];
    __shared__ float red[512];
    __shared__ float part[8][128];
    int len = lens[b];
    const float* e0 = e_ws + b * TT;
    const float* e1 = e_ws + 51200 + b * TT;
    float mx = -3.4e38f;
    for (int t = tid; t < len; t += 512) mx = fmaxf(mx, e0[t] + e1[t]);
    red[tid] = mx; __syncthreads();
    for (int s = 256; s > 0; s >>= 1) {
        if (tid < s) red[tid] = fmaxf(red[tid], red[tid + s]);
        __syncthreads();
    }
    mx = red[0]; __syncthreads();
    float sum = 0.f;
    for (int t = tid; t < TT; t += 512) {
        float p = (t < len) ? expf(2.f * (e0[t] + e1[t] - mx)) : 0.f;
        w_sm[t] = p; sum += p;
    }
    red[tid] = sum; __syncthreads();
    for (int s = 256; s > 0; s >>= 1) {
        if (tid < s) red[tid] += red[tid + s];
        __syncthreads();
    }
    float inv = 1.f / red[0];
    __syncthreads();
    for (int t = tid; t < TT; t += 512) {
        float wv = w_sm[t] * inv;
        w_sm[t] = wv;
        if (ch == 0) w_out[b * TT + t] = wv;
    }
    __syncthreads();
    // ctx: wave w8 covers t in [w8*200, w8*200+200), lanes cover 128 cols as float2
    int lane2 = tid & 63, w8 = tid >> 6;
    int tb = w8 * 200;
    const float* base = enc + (size_t)(b * TT + tb) * EE + ch * 128 + lane2 * 2;
    float cx = 0.f, cy = 0.f;
    #pragma unroll 1
    for (int i = 0; i < 200; i += 8) {
        #pragma unroll
        for (int j = 0; j < 8; ++j) {
            float2 v = *reinterpret_cast<const float2*>(base + (size_t)(i + j) * EE);
            float ww = w_sm[tb + i + j];
            cx += ww * v.x; cy += ww * v.y;
        }
    }
    part[w8][lane2 * 2] = cx;
    part[w8][lane2 * 2 + 1] = cy;
    __syncthreads();
    if (tid < 128) {
        float s = 0.f;
        #pragma unroll
        for (int i = 0; i < 8; ++i) s += part[i][tid];
        ctx[b * EE + ch * 128 + tid] = s;
    }
}

extern "C" void kernel_launch(void* const* d_in, const int* in_sizes, int n_in,
                              void* d_out, int out_size, void* d_ws, size_t ws_size,
                              hipStream_t stream) {
    const float* enc      = (const float*)d_in[0];
    const int*   lens     = (const int*)d_in[1];
    const float* dec_z    = (const float*)d_in[2];
    const float* att_prev = (const float*)d_in[3];
    const float* att_h    = (const float*)d_in[4];
    const float* att_c    = (const float*)d_in[5];
    const float* W_enc    = (const float*)d_in[6];
    const float* b_enc    = (const float*)d_in[7];
    const float* W_dec    = (const float*)d_in[8];
    const float* conv_w   = (const float*)d_in[9];
    const float* W_ih     = (const float*)d_in[10];
    const float* W_hh     = (const float*)d_in[11];
    const float* W_g      = (const float*)d_in[12];

    float* out = (float*)d_out;
    float* ws  = (float*)d_ws;
    float* af   = ws + AF_OFF;
    float* r_ws = ws + R_OFF;
    float* e_ws = ws + E_OFF;
    unsigned short* Wbf = (unsigned short*)(ws + WBF_OFF);

    prep_kernel<<<832, 256, 0, stream>>>(att_prev, conv_w, W_enc, af, Wbf);
    gates_lstm_kernel<<<256, 512, 0, stream>>>(af, att_h, dec_z, att_c,
                                               W_ih, W_hh, W_dec, out, r_ws);
    score_gemm_kernel<<<800, 512, 0, stream>>>(enc, Wbf, b_enc, r_ws, W_g, e_ws);
    ctx_softmax_kernel<<<dim3(BB, 8), 512, 0, stream>>>(enc, e_ws, lens,
                                                        out + W_OFF, out + CTX_OFF);
}